// Round 9
// baseline (273.532 us; speedup 1.0000x reference)
//
#include <hip/hip_runtime.h>

// B=4, T=2048, DIM=1024, H=16, Dh=64. fp32 in/out, bf16 internal.
// ws layout (bytes):
//   xn     @ 0          : 8192x1024 bf16  (16 MB)
//   wqkvT  @ 16777216   : 3072x1024 bf16  ( 6 MB)
//   woutT  @ 23068672   : 1024x1024 bf16  ( 2 MB)
//   qkv    @ 25165824   : q,k: [b][h][t][d]; v: [b][h][d][t] bf16 (48 MB)
//          q pre-scaled by 0.125*log2(e)  (softmax runs in exp2 domain)
//   attno  @ 75497472   : 8192x1024 bf16  (16 MB)   [b*T+t][h*64+d]

#define DIMX 1024
#define TSEQ 2048
#define NB 4
#define NH 16
#define DH 64
#define NROWS (NB * TSEQ)
#define QSCALE 0.18033688011112042f /* 0.125 * log2(e) */

typedef __bf16 bf16_t;
typedef __bf16 bf16x8 __attribute__((ext_vector_type(8)));
typedef __bf16 bf16x4 __attribute__((ext_vector_type(4)));
typedef float f32x4 __attribute__((ext_vector_type(4)));

#if __has_builtin(__builtin_amdgcn_exp2f)
#define EXP2F __builtin_amdgcn_exp2f
#else
#define EXP2F exp2f
#endif

__device__ __forceinline__ bf16x4 cvt4(f32x4 v) {
    return __builtin_convertvector(v, bf16x4);  // fptrunc RNE -> v_cvt_pk_bf16_f32
}
__device__ __forceinline__ void async16(const bf16_t* g, bf16_t* l) {
    __builtin_amdgcn_global_load_lds(
        (const __attribute__((address_space(1))) unsigned int*)g,
        (__attribute__((address_space(3))) unsigned int*)l, 16, 0, 0);
}

// ---------------- Fused prep: LayerNorm + both weight transposes ------------
__global__ __launch_bounds__(256) void prep_kernel(
    const float* __restrict__ x, const float* __restrict__ g,
    const float* __restrict__ b, bf16_t* __restrict__ xn,
    const float* __restrict__ w_qkv, bf16_t* __restrict__ wqkvT,
    const float* __restrict__ w_out, bf16_t* __restrict__ woutT) {
    int bid = blockIdx.x, tid = threadIdx.x;
    if (bid < NROWS) {
        int row = bid;
        const float4 xv = *(const float4*)(x + (size_t)row * DIMX + tid * 4);
        float s = xv.x + xv.y + xv.z + xv.w;
        float q = xv.x * xv.x + xv.y * xv.y + xv.z * xv.z + xv.w * xv.w;
        for (int o = 32; o > 0; o >>= 1) {
            s += __shfl_xor(s, o);
            q += __shfl_xor(q, o);
        }
        __shared__ float2 red[4];
        int wave = tid >> 6, lane = tid & 63;
        if (lane == 0) red[wave] = make_float2(s, q);
        __syncthreads();
        float2 r0 = red[0], r1 = red[1], r2 = red[2], r3 = red[3];
        s = r0.x + r1.x + r2.x + r3.x;
        q = r0.y + r1.y + r2.y + r3.y;
        float mu = s * (1.0f / DIMX);
        float var = q * (1.0f / DIMX) - mu * mu;
        float rstd = rsqrtf(var + 1e-5f);
        float4 gv = *(const float4*)(g + tid * 4);
        float4 bv = *(const float4*)(b + tid * 4);
        f32x4 r;
        r[0] = (xv.x - mu) * rstd * gv.x + bv.x;
        r[1] = (xv.y - mu) * rstd * gv.y + bv.y;
        r[2] = (xv.z - mu) * rstd * gv.z + bv.z;
        r[3] = (xv.w - mu) * rstd * gv.w + bv.w;
        *(bf16x4*)(xn + (size_t)row * DIMX + tid * 4) = cvt4(r);
    } else {
        const float* src;
        bf16_t* dst;
        int R, C, tb;
        if (bid < NROWS + 3072) {
            tb = bid - NROWS; src = w_qkv; dst = wqkvT; R = 1024; C = 3072;
        } else {
            tb = bid - NROWS - 3072; src = w_out; dst = woutT; R = 1024; C = 1024;
        }
        int ntx = C >> 5;
        int c0 = (tb % ntx) * 32, r0 = (tb / ntx) * 32;
        int tx = tid & 31, ty = tid >> 5;  // 32 x 8
        __shared__ float tile[32][33];
        for (int i = ty; i < 32; i += 8)
            tile[i][tx] = src[(size_t)(r0 + i) * C + c0 + tx];
        __syncthreads();
        for (int i = ty; i < 32; i += 8)
            dst[(size_t)(c0 + i) * R + r0 + tx] = (bf16_t)tile[tx][i];
    }
}

#define MFMA16 __builtin_amdgcn_mfma_f32_16x16x32_bf16

// ---------------- epilogue shared by GEMM ----------------
template <int MODE>
__device__ __forceinline__ void gemm_epilogue(
    f32x4 (&acc)[4][4], void* Cout, const float* bias,
    int m0, int n0, int wr, int wc, int lm, int quad, int N) {
#pragma unroll
    for (int mt = 0; mt < 4; ++mt) {
#pragma unroll
        for (int nt = 0; nt < 4; ++nt) {
            int m = m0 + wr * 64 + mt * 16 + quad * 4;  // +r
            int n = n0 + wc * 64 + nt * 16 + lm;
            if (MODE == 1) {
                int sel = n >> 10, nn = n & 1023, h = nn >> 6, d = nn & 63;
                int b = m >> 11, t = m & 2047;
                if (sel == 2) {
                    *(bf16x4*)((bf16_t*)Cout + (size_t)2 * 8388608 +
                               ((size_t)((b * NH + h) * DH + d)) * TSEQ + t) = cvt4(acc[mt][nt]);
                } else {
                    f32x4 sv = acc[mt][nt] * (sel == 0 ? QSCALE : 1.0f);
                    bf16x4 c4 = cvt4(sv);
#pragma unroll
                    for (int r = 0; r < 4; ++r)
                        ((bf16_t*)Cout)[(size_t)sel * 8388608 +
                                        ((size_t)((b * NH + h) * TSEQ + t + r)) * DH + d] = c4[r];
                }
            } else {
                float bn = bias[n];
#pragma unroll
                for (int r = 0; r < 4; ++r)
                    ((float*)Cout)[(size_t)(m + r) * N + n] = acc[mt][nt][r] + bn;
            }
        }
    }
}

// ---------------- 128x128 / BK=32 / 4-buffer COUNTED-vmcnt MFMA GEMM ---------
// C[m][n] = sum_k A[m][k]*BT[n][k]. 256 threads = 4 waves (2M x 2N), per-wave
// 64x64, acc[4][4]. LDS 64 KiB = 4 rotating buffers of A[128][32]+B[128][32]
// -> 2 blocks/CU. T4 discipline (m218: counted-vs-drain0 IS the pipeline
// gain; AITER: vmcnt never 0 in main loop): during K-tile kt stage tile kt+3
// into buf (kt+3)&3 (its readers finished two barriers ago -> WAR-safe),
// boundary waits vmcnt(8) = retire ONLY tile kt+1's 4 loads/thread, keep 8 in
// flight across the barrier. Tail peels vmcnt(4)/vmcnt(0). Swizzle: source
// granule ^= (row>>1)&3, matched on ds_read (linear LDS dest, rule 21).
template <int MODE>
__global__ __launch_bounds__(256, 2) void gemm128c(
    const bf16_t* __restrict__ A, const bf16_t* __restrict__ BT,
    void* __restrict__ Cout, const float* __restrict__ bias, int M, int N, int K) {
    __shared__ __align__(16) bf16_t As[4][128 * 32];
    __shared__ __align__(16) bf16_t Bs[4][128 * 32];
    int tid = threadIdx.x, lane = tid & 63, wave = tid >> 6;
    int lm = lane & 15, quad = lane >> 4;
    int wr = wave >> 1, wc = wave & 1;

    // bijective XCD swizzle (nwg % 8 == 0 for both call sites)
    int nbx = gridDim.x;
    int nwg = nbx * gridDim.y;
    int linear = blockIdx.y * nbx + blockIdx.x;
    int cpx = nwg >> 3;
    int swz = (linear & 7) * cpx + (linear >> 3);
    int bx = swz % nbx, by = swz / nbx;
    int m0 = by * 128, n0 = bx * 128;

    // staging: issue i covers row i*64+(tid>>2), granule tid&3; source granule
    // ^= (row>>1)&3 = (tid>>3)&3 (i-invariant, 64 = 0 mod 4 after >>1&3).
    int srow = tid >> 2;
    int scol = ((tid & 3) ^ ((tid >> 3) & 3)) << 3;
    const bf16_t* ga = A + (size_t)(m0 + srow) * K + scol;
    const bf16_t* gb = BT + (size_t)(n0 + srow) * K + scol;
    int ldst = tid * 8;

    // frag-read granule: quad ^ ((lm>>1)&3) (row = base16*t + lm)
    int swr = ((quad ^ ((lm >> 1) & 3)) << 3);

    f32x4 zero = {0.f, 0.f, 0.f, 0.f};
    f32x4 acc[4][4];
#pragma unroll
    for (int i = 0; i < 4; ++i)
#pragma unroll
        for (int j = 0; j < 4; ++j) acc[i][j] = zero;

#define STAGE_TILE(buf, kk)                                                   \
    do {                                                                      \
        async16(ga + (kk), &As[buf][ldst]);                                   \
        async16(ga + (size_t)64 * K + (kk), &As[buf][2048 + ldst]);           \
        async16(gb + (kk), &Bs[buf][ldst]);                                   \
        async16(gb + (size_t)64 * K + (kk), &Bs[buf][2048 + ldst]);           \
    } while (0)

#define GEMM_BODY(buf)                                                        \
    do {                                                                      \
        const bf16_t* pa = &As[buf][0];                                       \
        const bf16_t* pb = &Bs[buf][0];                                       \
        bf16x8 af[4], bfr[4];                                                 \
        _Pragma("unroll")                                                     \
        for (int t = 0; t < 4; ++t)                                           \
            af[t] = *(const bf16x8*)&pa[(wr * 64 + t * 16 + lm) * 32 + swr];  \
        _Pragma("unroll")                                                     \
        for (int t = 0; t < 4; ++t)                                           \
            bfr[t] = *(const bf16x8*)&pb[(wc * 64 + t * 16 + lm) * 32 + swr]; \
        asm volatile("s_waitcnt lgkmcnt(0)" ::: "memory");                    \
        __builtin_amdgcn_s_setprio(1);                                        \
        _Pragma("unroll")                                                     \
        for (int mt = 0; mt < 4; ++mt)                                        \
            _Pragma("unroll")                                                 \
            for (int nt = 0; nt < 4; ++nt)                                    \
                acc[mt][nt] = MFMA16(af[mt], bfr[nt], acc[mt][nt], 0, 0, 0);  \
        __builtin_amdgcn_s_setprio(0);                                        \
    } while (0)

    // prologue: stage tiles 0,1,2; wait for tile 0 only (8 loads stay in flight)
    STAGE_TILE(0, 0);
    STAGE_TILE(1, 32);
    STAGE_TILE(2, 64);
    asm volatile("s_waitcnt vmcnt(8)" ::: "memory");
    __builtin_amdgcn_s_barrier();

    int nkt = K >> 5;
    for (int kt = 0; kt + 3 < nkt; ++kt) {
        STAGE_TILE((kt + 3) & 3, (size_t)(kt + 3) * 32);
        GEMM_BODY(kt & 3);
        // retire ONLY tile kt+1's loads; tiles kt+2,kt+3 stay in flight
        asm volatile("s_waitcnt vmcnt(8)" ::: "memory");
        __builtin_amdgcn_s_barrier();
    }
    // kt = nkt-3: no stage; retire tile nkt-2's loads (tile nkt-1 in flight)
    GEMM_BODY((nkt - 3) & 3);
    asm volatile("s_waitcnt vmcnt(4)" ::: "memory");
    __builtin_amdgcn_s_barrier();
    // kt = nkt-2: retire the last loads
    GEMM_BODY((nkt - 2) & 3);
    asm volatile("s_waitcnt vmcnt(0)" ::: "memory");
    __builtin_amdgcn_s_barrier();
    // kt = nkt-1
    GEMM_BODY((nkt - 1) & 3);

#undef STAGE_TILE
#undef GEMM_BODY

    gemm_epilogue<MODE>(acc, Cout, bias, m0, n0, wr, wc, lm, quad, N);
}

// ---------------- MFMA flash attention, 8 waves x 32 q-rows, KVBLK=128 ------
// (unchanged; at the serialized MFMA+VALU work-sum floor, ~82 us)
__global__ __launch_bounds__(512, 4) void attn_mfma(
    const bf16_t* __restrict__ qkv, bf16_t* __restrict__ o) {
    int bh = blockIdx.y;
    int qt = blockIdx.x;  // 256-row q tile
    const bf16_t* qb = qkv + (size_t)bh * TSEQ * DH;
    const bf16_t* kb = qkv + (size_t)8388608 + (size_t)bh * TSEQ * DH;
    const bf16_t* vb = qkv + (size_t)16777216 + (size_t)bh * DH * TSEQ;  // [d][t]
    int tid = threadIdx.x, wave = tid >> 6, lane = tid & 63;
    int lm = lane & 15, quad = lane >> 4, lx = lm & 7;

    __shared__ __align__(16) bf16_t Ks[2][2][64 * 64];  // [buf][sub]
    __shared__ __align__(16) bf16_t Vt[2][2][64 * 64];  // [buf][sub]

    int roff = tid >> 3;
    int fr = (roff & 3) | ((roff & 8) >> 1);
    int cperm = ((tid & 7) ^ fr) * 8;
    const bf16_t* kp = kb + (size_t)roff * DH + cperm;
    const bf16_t* vp = vb + (size_t)roff * TSEQ + cperm;
    int l0 = tid * 8;  // linear LDS dest granule

    bf16x8 qf[2][2];
#pragma unroll
    for (int u = 0; u < 2; ++u)
#pragma unroll
        for (int ks = 0; ks < 2; ++ks)
            qf[u][ks] = *(const bf16x8*)(qb +
                (size_t)(qt * 256 + wave * 32 + u * 16 + lm) * DH + ks * 32 + quad * 8);

    f32x4 zero = {0.f, 0.f, 0.f, 0.f};
    f32x4 m16 = {-16.f, -16.f, -16.f, -16.f};
    f32x4 acc[2][4];  // [u][dt]
#pragma unroll
    for (int u = 0; u < 2; ++u)
#pragma unroll
        for (int dt = 0; dt < 4; ++dt) acc[u][dt] = zero;
    f32x4 l4[2] = {zero, zero};

    int qh = lm >> 2, rr = lm & 3;
    int krow0 = 8 * qh + rr;
    int krow1 = krow0 + 4;
    int krow2 = 32 + 8 * (qh ^ 2) + rr;
    int krow3 = krow2 + 4;
    int fo0 = (quad ^ lx) * 8;
    int fo1 = ((4 + quad) ^ lx) * 8;
    int fv = (lm & 3) | ((lm & 8) >> 1);
    int vo0 = (quad ^ fv) * 8;
    int vo1 = ((4 | (quad ^ 2)) ^ fv) * 8;

    async16(kp, &Ks[0][0][l0]);
    async16(kp + (size_t)64 * DH, &Ks[0][1][l0]);
    async16(vp, &Vt[0][0][l0]);
    async16(vp + 64, &Vt[0][1][l0]);
    kp += 128 * DH; vp += 128;
    asm volatile("s_waitcnt vmcnt(0)" ::: "memory");
    __builtin_amdgcn_s_barrier();

    for (int jt = 0; jt < TSEQ / 128; ++jt) {  // 16 iterations
        int c = jt & 1;
        if (jt + 1 < TSEQ / 128) {
            async16(kp, &Ks[c ^ 1][0][l0]);
            async16(kp + (size_t)64 * DH, &Ks[c ^ 1][1][l0]);
            async16(vp, &Vt[c ^ 1][0][l0]);
            async16(vp + 64, &Vt[c ^ 1][1][l0]);
            kp += 128 * DH; vp += 128;
        }

#pragma unroll
        for (int sub = 0; sub < 2; ++sub) {
            const bf16_t* Kc = &Ks[c][sub][0];
            const bf16_t* Vc = &Vt[c][sub][0];

            bf16x8 kf[4][2];
            kf[0][0] = *(const bf16x8*)&Kc[krow0 * 64 + fo0];
            kf[0][1] = *(const bf16x8*)&Kc[krow0 * 64 + fo1];
            kf[1][0] = *(const bf16x8*)&Kc[krow1 * 64 + fo0];
            kf[1][1] = *(const bf16x8*)&Kc[krow1 * 64 + fo1];
            kf[2][0] = *(const bf16x8*)&Kc[krow2 * 64 + fo0];
            kf[2][1] = *(const bf16x8*)&Kc[krow2 * 64 + fo1];
            kf[3][0] = *(const bf16x8*)&Kc[krow3 * 64 + fo0];
            kf[3][1] = *(const bf16x8*)&Kc[krow3 * 64 + fo1];

            bf16x8 pf[2][2];
#pragma unroll
            for (int u = 0; u < 2; ++u) {
                f32x4 s[4];
                __builtin_amdgcn_s_setprio(1);
#pragma unroll
                for (int nt = 0; nt < 4; ++nt) {
                    s[nt] = __builtin_amdgcn_mfma_f32_16x16x32_bf16(kf[nt][0], qf[u][0], m16, 0, 0, 0);
                    s[nt] = __builtin_amdgcn_mfma_f32_16x16x32_bf16(kf[nt][1], qf[u][1], s[nt], 0, 0, 0);
                }
                __builtin_amdgcn_s_setprio(0);
                f32x4 p[4];
#pragma unroll
                for (int nt = 0; nt < 4; ++nt) {
#pragma unroll
                    for (int e = 0; e < 4; ++e) p[nt][e] = EXP2F(s[nt][e]);
                    l4[u] += p[nt];
                }
                bf16x4 c0 = cvt4(p[0]), c1 = cvt4(p[1]), c2 = cvt4(p[2]), c3 = cvt4(p[3]);
                pf[u][0] = __builtin_shufflevector(c0, c1, 0, 1, 2, 3, 4, 5, 6, 7);
                pf[u][1] = __builtin_shufflevector(c2, c3, 0, 1, 2, 3, 4, 5, 6, 7);
            }

            __builtin_amdgcn_s_setprio(1);
#pragma unroll
            for (int dt = 0; dt < 4; ++dt) {
                bf16x8 vf0 = *(const bf16x8*)&Vc[(dt * 16 + lm) * 64 + vo0];
                bf16x8 vf1 = *(const bf16x8*)&Vc[(dt * 16 + lm) * 64 + vo1];
#pragma unroll
                for (int u = 0; u < 2; ++u) {
                    acc[u][dt] = __builtin_amdgcn_mfma_f32_16x16x32_bf16(vf0, pf[u][0], acc[u][dt], 0, 0, 0);
                    acc[u][dt] = __builtin_amdgcn_mfma_f32_16x16x32_bf16(vf1, pf[u][1], acc[u][dt], 0, 0, 0);
                }
            }
            __builtin_amdgcn_s_setprio(0);
        }

        asm volatile("s_waitcnt vmcnt(0)" ::: "memory");
        __builtin_amdgcn_s_barrier();
    }

    int b = bh >> 4, h = bh & 15;
#pragma unroll
    for (int u = 0; u < 2; ++u) {
        float l = (l4[u][0] + l4[u][1]) + (l4[u][2] + l4[u][3]);
        l += __shfl_xor(l, 16);
        l += __shfl_xor(l, 32);
        float rl = 1.0f / l;
        int t = qt * 256 + wave * 32 + u * 16 + lm;
#pragma unroll
        for (int dt = 0; dt < 4; ++dt) {
            f32x4 ov = acc[u][dt] * rl;
            *(bf16x4*)(o + ((size_t)(b * TSEQ + t)) * DIMX + h * DH + dt * 16 + quad * 4) = cvt4(ov);
        }
    }
}

extern "C" void kernel_launch(void* const* d_in, const int* in_sizes, int n_in,
                              void* d_out, int out_size, void* d_ws, size_t ws_size,
                              hipStream_t stream) {
    const float* x = (const float*)d_in[0];
    const float* g = (const float*)d_in[1];
    const float* be = (const float*)d_in[2];
    const float* w_qkv = (const float*)d_in[3];
    const float* w_out = (const float*)d_in[4];
    const float* b_out = (const float*)d_in[5];
    float* out = (float*)d_out;
    char* ws = (char*)d_ws;

    bf16_t* xn = (bf16_t*)(ws);
    bf16_t* wqkvT = (bf16_t*)(ws + 16777216);
    bf16_t* woutT = (bf16_t*)(ws + 23068672);
    bf16_t* qkv = (bf16_t*)(ws + 25165824);
    bf16_t* attno = (bf16_t*)(ws + 75497472);

    prep_kernel<<<NROWS + 3072 + 1024, 256, 0, stream>>>(
        x, g, be, xn, w_qkv, wqkvT, w_out, woutT);
    gemm128c<1><<<dim3(24, 64), 256, 0, stream>>>(xn, wqkvT, (void*)qkv, nullptr, NROWS, 3072, 1024);
    attn_mfma<<<dim3(8, 64), 512, 0, stream>>>(qkv, attno);
    gemm128c<2><<<dim3(8, 64), 256, 0, stream>>>(attno, woutT, (void*)out, b_out, NROWS, 1024, 1024);
}

// Round 10
// 252.428 us; speedup vs baseline: 1.0836x; 1.0836x over previous
//
#include <hip/hip_runtime.h>

// B=4, T=2048, DIM=1024, H=16, Dh=64. fp32 in/out, bf16 internal.
// ws layout (bytes):
//   xn     @ 0          : 8192x1024 bf16  (16 MB)
//   wqkvT  @ 16777216   : 3072x1024 bf16  ( 6 MB)
//   woutT  @ 23068672   : 1024x1024 bf16  ( 2 MB)
//   qkv    @ 25165824   : q,k: [b][h][t][d]; v: [b][h][d][t] bf16 (48 MB)
//          q pre-scaled by 0.125*log2(e)  (softmax runs in exp2 domain)
//   attno  @ 75497472   : 8192x1024 bf16  (16 MB)   [b*T+t][h*64+d]

#define DIMX 1024
#define TSEQ 2048
#define NB 4
#define NH 16
#define DH 64
#define NROWS (NB * TSEQ)
#define QSCALE 0.18033688011112042f /* 0.125 * log2(e) */

typedef __bf16 bf16_t;
typedef __bf16 bf16x8 __attribute__((ext_vector_type(8)));
typedef __bf16 bf16x4 __attribute__((ext_vector_type(4)));
typedef float f32x4 __attribute__((ext_vector_type(4)));

#if __has_builtin(__builtin_amdgcn_exp2f)
#define EXP2F __builtin_amdgcn_exp2f
#else
#define EXP2F exp2f
#endif

__device__ __forceinline__ bf16x4 cvt4(f32x4 v) {
    return __builtin_convertvector(v, bf16x4);  // fptrunc RNE -> v_cvt_pk_bf16_f32
}
__device__ __forceinline__ void async16(const bf16_t* g, bf16_t* l) {
    __builtin_amdgcn_global_load_lds(
        (const __attribute__((address_space(1))) unsigned int*)g,
        (__attribute__((address_space(3))) unsigned int*)l, 16, 0, 0);
}

// ---------------- Fused prep: LayerNorm + both weight transposes ------------
__global__ __launch_bounds__(256) void prep_kernel(
    const float* __restrict__ x, const float* __restrict__ g,
    const float* __restrict__ b, bf16_t* __restrict__ xn,
    const float* __restrict__ w_qkv, bf16_t* __restrict__ wqkvT,
    const float* __restrict__ w_out, bf16_t* __restrict__ woutT) {
    int bid = blockIdx.x, tid = threadIdx.x;
    if (bid < NROWS) {
        int row = bid;
        const float4 xv = *(const float4*)(x + (size_t)row * DIMX + tid * 4);
        float s = xv.x + xv.y + xv.z + xv.w;
        float q = xv.x * xv.x + xv.y * xv.y + xv.z * xv.z + xv.w * xv.w;
        for (int o = 32; o > 0; o >>= 1) {
            s += __shfl_xor(s, o);
            q += __shfl_xor(q, o);
        }
        __shared__ float2 red[4];
        int wave = tid >> 6, lane = tid & 63;
        if (lane == 0) red[wave] = make_float2(s, q);
        __syncthreads();
        float2 r0 = red[0], r1 = red[1], r2 = red[2], r3 = red[3];
        s = r0.x + r1.x + r2.x + r3.x;
        q = r0.y + r1.y + r2.y + r3.y;
        float mu = s * (1.0f / DIMX);
        float var = q * (1.0f / DIMX) - mu * mu;
        float rstd = rsqrtf(var + 1e-5f);
        float4 gv = *(const float4*)(g + tid * 4);
        float4 bv = *(const float4*)(b + tid * 4);
        f32x4 r;
        r[0] = (xv.x - mu) * rstd * gv.x + bv.x;
        r[1] = (xv.y - mu) * rstd * gv.y + bv.y;
        r[2] = (xv.z - mu) * rstd * gv.z + bv.z;
        r[3] = (xv.w - mu) * rstd * gv.w + bv.w;
        *(bf16x4*)(xn + (size_t)row * DIMX + tid * 4) = cvt4(r);
    } else {
        const float* src;
        bf16_t* dst;
        int R, C, tb;
        if (bid < NROWS + 3072) {
            tb = bid - NROWS; src = w_qkv; dst = wqkvT; R = 1024; C = 3072;
        } else {
            tb = bid - NROWS - 3072; src = w_out; dst = woutT; R = 1024; C = 1024;
        }
        int ntx = C >> 5;
        int c0 = (tb % ntx) * 32, r0 = (tb / ntx) * 32;
        int tx = tid & 31, ty = tid >> 5;  // 32 x 8
        __shared__ float tile[32][33];
        for (int i = ty; i < 32; i += 8)
            tile[i][tx] = src[(size_t)(r0 + i) * C + c0 + tx];
        __syncthreads();
        for (int i = ty; i < 32; i += 8)
            dst[(size_t)(c0 + i) * R + r0 + tx] = (bf16_t)tile[tx][i];
    }
}

#define MFMA16 __builtin_amdgcn_mfma_f32_16x16x32_bf16

// ---------------- epilogue shared by GEMM ----------------
template <int MODE>
__device__ __forceinline__ void gemm_epilogue(
    f32x4 (&acc)[4][4], void* Cout, const float* bias,
    int m0, int n0, int wr, int wc, int lm, int quad, int N) {
#pragma unroll
    for (int mt = 0; mt < 4; ++mt) {
#pragma unroll
        for (int nt = 0; nt < 4; ++nt) {
            int m = m0 + wr * 64 + mt * 16 + quad * 4;  // +r
            int n = n0 + wc * 64 + nt * 16 + lm;
            if (MODE == 1) {
                int sel = n >> 10, nn = n & 1023, h = nn >> 6, d = nn & 63;
                int b = m >> 11, t = m & 2047;
                if (sel == 2) {
                    *(bf16x4*)((bf16_t*)Cout + (size_t)2 * 8388608 +
                               ((size_t)((b * NH + h) * DH + d)) * TSEQ + t) = cvt4(acc[mt][nt]);
                } else {
                    f32x4 sv = acc[mt][nt] * (sel == 0 ? QSCALE : 1.0f);
                    bf16x4 c4 = cvt4(sv);
#pragma unroll
                    for (int r = 0; r < 4; ++r)
                        ((bf16_t*)Cout)[(size_t)sel * 8388608 +
                                        ((size_t)((b * NH + h) * TSEQ + t + r)) * DH + d] = c4[r];
                }
            } else {
                float bn = bias[n];
#pragma unroll
                for (int r = 0; r < 4; ++r)
                    ((float*)Cout)[(size_t)(m + r) * N + n] = acc[mt][nt][r] + bn;
            }
        }
    }
}

// ---------------- 128x128 / BK=64 / 2-phase MFMA GEMM (r5, best measured) ----
// 256 threads = 4 waves (2M x 2N), per-wave 64x64 output, acc[4][4].
// LDS 64 KiB (dbuf A[128][64]+B[128][64]) -> 2 blocks/CU; their phase drift
// hides each other's barrier/drain stalls. Staging via global_load_lds(16B),
// source-granule swizzle c8 ^= row&7, matched on ds_read (rule 21).
// 2 phases per K-tile; all 8 next-tile stages issued at P0; single vmcnt(0)
// at the tile boundary. This exact structure measured best across r4-r9
// (1-phase, BK=32 drain-0, BK=32 counted 4-buf all regressed).
template <int MODE>
__global__ __launch_bounds__(256, 2) void gemm128p(
    const bf16_t* __restrict__ A, const bf16_t* __restrict__ BT,
    void* __restrict__ Cout, const float* __restrict__ bias, int M, int N, int K) {
    __shared__ __align__(16) bf16_t As[2][128 * 64];
    __shared__ __align__(16) bf16_t Bs[2][128 * 64];
    int tid = threadIdx.x, lane = tid & 63, wave = tid >> 6;
    int lm = lane & 15, quad = lane >> 4;
    int wr = wave >> 1, wc = wave & 1;

    // bijective XCD swizzle (nwg % 8 == 0 for both call sites)
    int nbx = gridDim.x;
    int nwg = nbx * gridDim.y;
    int linear = blockIdx.y * nbx + blockIdx.x;
    int cpx = nwg >> 3;
    int swz = (linear & 7) * cpx + (linear >> 3);
    int bx = swz % nbx, by = swz / nbx;
    int m0 = by * 128, n0 = bx * 128;

    int srow = tid >> 3, sc8 = tid & 7;
    int scol = (sc8 ^ (srow & 7)) << 3;
    const bf16_t* ga = A + (size_t)(m0 + srow) * K + scol;
    const bf16_t* gb = BT + (size_t)(n0 + srow) * K + scol;
    int ldst = tid << 3;

    int sw0 = ((quad ^ (lm & 7)) << 3);
    int sw1 = (((4 + quad) ^ (lm & 7)) << 3);

    f32x4 zero = {0.f, 0.f, 0.f, 0.f};
    f32x4 acc[4][4];
#pragma unroll
    for (int i = 0; i < 4; ++i)
#pragma unroll
        for (int j = 0; j < 4; ++j) acc[i][j] = zero;

#pragma unroll
    for (int i = 0; i < 4; ++i) async16(ga + (size_t)(i * 32) * K, &As[0][i * 2048 + ldst]);
#pragma unroll
    for (int i = 0; i < 4; ++i) async16(gb + (size_t)(i * 32) * K, &Bs[0][i * 2048 + ldst]);
    asm volatile("s_waitcnt vmcnt(0)" ::: "memory");
    __builtin_amdgcn_s_barrier();

    int nkt = K >> 6;
    for (int kt = 0; kt < nkt; ++kt) {
        int c = kt & 1;
        int k1 = (kt + 1) << 6;
        bool pf = (kt + 1) < nkt;
        const bf16_t* pa = &As[c][0];
        const bf16_t* pb = &Bs[c][0];
        bf16_t* na = &As[c ^ 1][0];
        bf16_t* nb = &Bs[c ^ 1][0];
        bf16x8 af[4][2], bfr[2][2];

        // ---- phase 0: read A(mt0-3) + B(nt0-1); issue ALL next-tile stages ----
#pragma unroll
        for (int t = 0; t < 4; ++t) {
            int ro = (wr * 64 + t * 16 + lm) * 64;
            af[t][0] = *(const bf16x8*)&pa[ro + sw0];
            af[t][1] = *(const bf16x8*)&pa[ro + sw1];
        }
#pragma unroll
        for (int t = 0; t < 2; ++t) {
            int ro = (wc * 64 + t * 16 + lm) * 64;
            bfr[t][0] = *(const bf16x8*)&pb[ro + sw0];
            bfr[t][1] = *(const bf16x8*)&pb[ro + sw1];
        }
        if (pf) {
#pragma unroll
            for (int i = 0; i < 4; ++i)
                async16(ga + (size_t)(i * 32) * K + k1, &na[i * 2048 + ldst]);
#pragma unroll
            for (int i = 0; i < 4; ++i)
                async16(gb + (size_t)(i * 32) * K + k1, &nb[i * 2048 + ldst]);
        }
        __builtin_amdgcn_s_barrier();
        asm volatile("s_waitcnt lgkmcnt(0)" ::: "memory");
        __builtin_amdgcn_s_setprio(1);
#pragma unroll
        for (int mt = 0; mt < 4; ++mt)
#pragma unroll
            for (int nt = 0; nt < 2; ++nt) {
                acc[mt][nt] = MFMA16(af[mt][0], bfr[nt][0], acc[mt][nt], 0, 0, 0);
                acc[mt][nt] = MFMA16(af[mt][1], bfr[nt][1], acc[mt][nt], 0, 0, 0);
            }
        __builtin_amdgcn_s_setprio(0);
        __builtin_amdgcn_s_barrier();

        // ---- phase 1: read B(nt2-3), reuse A(mt0-3); tile boundary ----
#pragma unroll
        for (int t = 0; t < 2; ++t) {
            int ro = (wc * 64 + (2 + t) * 16 + lm) * 64;
            bfr[t][0] = *(const bf16x8*)&pb[ro + sw0];
            bfr[t][1] = *(const bf16x8*)&pb[ro + sw1];
        }
        __builtin_amdgcn_s_barrier();
        asm volatile("s_waitcnt lgkmcnt(0)" ::: "memory");
        __builtin_amdgcn_s_setprio(1);
#pragma unroll
        for (int mt = 0; mt < 4; ++mt)
#pragma unroll
            for (int nt = 0; nt < 2; ++nt) {
                acc[mt][2 + nt] = MFMA16(af[mt][0], bfr[nt][0], acc[mt][2 + nt], 0, 0, 0);
                acc[mt][2 + nt] = MFMA16(af[mt][1], bfr[nt][1], acc[mt][2 + nt], 0, 0, 0);
            }
        __builtin_amdgcn_s_setprio(0);
        asm volatile("s_waitcnt vmcnt(0)" ::: "memory");
        __builtin_amdgcn_s_barrier();
    }

    gemm_epilogue<MODE>(acc, Cout, bias, m0, n0, wr, wc, lm, quad, N);
}

// ---------------- MFMA flash attention, 8 waves x 32 q-rows, KVBLK=128 ------
// r5 structure (register-resident P via K-row permutation, double-buffered
// K/V, no-max exp2 softmax). NEW: per sub-tile, BOTH q-subtiles' QK^T MFMAs
// are issued back-to-back BEFORE either softmax, so each wave's exp/pack
// VALU for u0 executes under u1's MFMA pipe occupancy (intra-wave
// MFMA||VALU overlap; the old order put dependent VALU between the MFMA
// groups). Costs +16 VGPR for s held across both u (64 -> ~80, cap 128).
__global__ __launch_bounds__(512, 4) void attn_mfma(
    const bf16_t* __restrict__ qkv, bf16_t* __restrict__ o) {
    int bh = blockIdx.y;
    int qt = blockIdx.x;  // 256-row q tile
    const bf16_t* qb = qkv + (size_t)bh * TSEQ * DH;
    const bf16_t* kb = qkv + (size_t)8388608 + (size_t)bh * TSEQ * DH;
    const bf16_t* vb = qkv + (size_t)16777216 + (size_t)bh * DH * TSEQ;  // [d][t]
    int tid = threadIdx.x, wave = tid >> 6, lane = tid & 63;
    int lm = lane & 15, quad = lane >> 4, lx = lm & 7;

    __shared__ __align__(16) bf16_t Ks[2][2][64 * 64];  // [buf][sub]
    __shared__ __align__(16) bf16_t Vt[2][2][64 * 64];  // [buf][sub]

    int roff = tid >> 3;
    int fr = (roff & 3) | ((roff & 8) >> 1);
    int cperm = ((tid & 7) ^ fr) * 8;
    const bf16_t* kp = kb + (size_t)roff * DH + cperm;
    const bf16_t* vp = vb + (size_t)roff * TSEQ + cperm;
    int l0 = tid * 8;  // linear LDS dest granule

    bf16x8 qf[2][2];
#pragma unroll
    for (int u = 0; u < 2; ++u)
#pragma unroll
        for (int ks = 0; ks < 2; ++ks)
            qf[u][ks] = *(const bf16x8*)(qb +
                (size_t)(qt * 256 + wave * 32 + u * 16 + lm) * DH + ks * 32 + quad * 8);

    f32x4 zero = {0.f, 0.f, 0.f, 0.f};
    f32x4 m16 = {-16.f, -16.f, -16.f, -16.f};
    f32x4 acc[2][4];  // [u][dt]
#pragma unroll
    for (int u = 0; u < 2; ++u)
#pragma unroll
        for (int dt = 0; dt < 4; ++dt) acc[u][dt] = zero;
    f32x4 l4[2] = {zero, zero};

    int qh = lm >> 2, rr = lm & 3;
    int krow0 = 8 * qh + rr;
    int krow1 = krow0 + 4;
    int krow2 = 32 + 8 * (qh ^ 2) + rr;
    int krow3 = krow2 + 4;
    int fo0 = (quad ^ lx) * 8;
    int fo1 = ((4 + quad) ^ lx) * 8;
    int fv = (lm & 3) | ((lm & 8) >> 1);
    int vo0 = (quad ^ fv) * 8;
    int vo1 = ((4 | (quad ^ 2)) ^ fv) * 8;

    async16(kp, &Ks[0][0][l0]);
    async16(kp + (size_t)64 * DH, &Ks[0][1][l0]);
    async16(vp, &Vt[0][0][l0]);
    async16(vp + 64, &Vt[0][1][l0]);
    kp += 128 * DH; vp += 128;
    asm volatile("s_waitcnt vmcnt(0)" ::: "memory");
    __builtin_amdgcn_s_barrier();

    for (int jt = 0; jt < TSEQ / 128; ++jt) {  // 16 iterations
        int c = jt & 1;
        if (jt + 1 < TSEQ / 128) {
            async16(kp, &Ks[c ^ 1][0][l0]);
            async16(kp + (size_t)64 * DH, &Ks[c ^ 1][1][l0]);
            async16(vp, &Vt[c ^ 1][0][l0]);
            async16(vp + 64, &Vt[c ^ 1][1][l0]);
            kp += 128 * DH; vp += 128;
        }

#pragma unroll
        for (int sub = 0; sub < 2; ++sub) {
            const bf16_t* Kc = &Ks[c][sub][0];
            const bf16_t* Vc = &Vt[c][sub][0];

            bf16x8 kf[4][2];
            kf[0][0] = *(const bf16x8*)&Kc[krow0 * 64 + fo0];
            kf[0][1] = *(const bf16x8*)&Kc[krow0 * 64 + fo1];
            kf[1][0] = *(const bf16x8*)&Kc[krow1 * 64 + fo0];
            kf[1][1] = *(const bf16x8*)&Kc[krow1 * 64 + fo1];
            kf[2][0] = *(const bf16x8*)&Kc[krow2 * 64 + fo0];
            kf[2][1] = *(const bf16x8*)&Kc[krow2 * 64 + fo1];
            kf[3][0] = *(const bf16x8*)&Kc[krow3 * 64 + fo0];
            kf[3][1] = *(const bf16x8*)&Kc[krow3 * 64 + fo1];

            // ---- QK^T for BOTH u first: 16 MFMAs issued back-to-back ----
            f32x4 s2[2][4];
            __builtin_amdgcn_s_setprio(1);
#pragma unroll
            for (int u = 0; u < 2; ++u)
#pragma unroll
                for (int nt = 0; nt < 4; ++nt) {
                    s2[u][nt] = __builtin_amdgcn_mfma_f32_16x16x32_bf16(kf[nt][0], qf[u][0], m16, 0, 0, 0);
                    s2[u][nt] = __builtin_amdgcn_mfma_f32_16x16x32_bf16(kf[nt][1], qf[u][1], s2[u][nt], 0, 0, 0);
                }
            __builtin_amdgcn_s_setprio(0);

            // ---- softmax for both u (u0's VALU overlaps u1's MFMA latency) ----
            bf16x8 pf[2][2];
#pragma unroll
            for (int u = 0; u < 2; ++u) {
                f32x4 p[4];
#pragma unroll
                for (int nt = 0; nt < 4; ++nt) {
#pragma unroll
                    for (int e = 0; e < 4; ++e) p[nt][e] = EXP2F(s2[u][nt][e]);
                    l4[u] += p[nt];
                }
                bf16x4 c0 = cvt4(p[0]), c1 = cvt4(p[1]), c2 = cvt4(p[2]), c3 = cvt4(p[3]);
                pf[u][0] = __builtin_shufflevector(c0, c1, 0, 1, 2, 3, 4, 5, 6, 7);
                pf[u][1] = __builtin_shufflevector(c2, c3, 0, 1, 2, 3, 4, 5, 6, 7);
            }

            __builtin_amdgcn_s_setprio(1);
#pragma unroll
            for (int dt = 0; dt < 4; ++dt) {
                bf16x8 vf0 = *(const bf16x8*)&Vc[(dt * 16 + lm) * 64 + vo0];
                bf16x8 vf1 = *(const bf16x8*)&Vc[(dt * 16 + lm) * 64 + vo1];
#pragma unroll
                for (int u = 0; u < 2; ++u) {
                    acc[u][dt] = __builtin_amdgcn_mfma_f32_16x16x32_bf16(vf0, pf[u][0], acc[u][dt], 0, 0, 0);
                    acc[u][dt] = __builtin_amdgcn_mfma_f32_16x16x32_bf16(vf1, pf[u][1], acc[u][dt], 0, 0, 0);
                }
            }
            __builtin_amdgcn_s_setprio(0);
        }

        asm volatile("s_waitcnt vmcnt(0)" ::: "memory");
        __builtin_amdgcn_s_barrier();
    }

    int b = bh >> 4, h = bh & 15;
#pragma unroll
    for (int u = 0; u < 2; ++u) {
        float l = (l4[u][0] + l4[u][1]) + (l4[u][2] + l4[u][3]);
        l += __shfl_xor(l, 16);
        l += __shfl_xor(l, 32);
        float rl = 1.0f / l;
        int t = qt * 256 + wave * 32 + u * 16 + lm;
#pragma unroll
        for (int dt = 0; dt < 4; ++dt) {
            f32x4 ov = acc[u][dt] * rl;
            *(bf16x4*)(o + ((size_t)(b * TSEQ + t)) * DIMX + h * DH + dt * 16 + quad * 4) = cvt4(ov);
        }
    }
}

extern "C" void kernel_launch(void* const* d_in, const int* in_sizes, int n_in,
                              void* d_out, int out_size, void* d_ws, size_t ws_size,
                              hipStream_t stream) {
    const float* x = (const float*)d_in[0];
    const float* g = (const float*)d_in[1];
    const float* be = (const float*)d_in[2];
    const float* w_qkv = (const float*)d_in[3];
    const float* w_out = (const float*)d_in[4];
    const float* b_out = (const float*)d_in[5];
    float* out = (float*)d_out;
    char* ws = (char*)d_ws;

    bf16_t* xn = (bf16_t*)(ws);
    bf16_t* wqkvT = (bf16_t*)(ws + 16777216);
    bf16_t* woutT = (bf16_t*)(ws + 23068672);
    bf16_t* qkv = (bf16_t*)(ws + 25165824);
    bf16_t* attno = (bf16_t*)(ws + 75497472);

    prep_kernel<<<NROWS + 3072 + 1024, 256, 0, stream>>>(
        x, g, be, xn, w_qkv, wqkvT, w_out, woutT);
    gemm128p<1><<<dim3(24, 64), 256, 0, stream>>>(xn, wqkvT, (void*)qkv, nullptr, NROWS, 3072, 1024);
    attn_mfma<<<dim3(8, 64), 512, 0, stream>>>(qkv, attno);
    gemm128p<2><<<dim3(8, 64), 256, 0, stream>>>(attno, woutT, (void*)out, b_out, NROWS, 1024, 1024);
}